// Round 1
// baseline (140.359 us; speedup 1.0000x reference)
//
#include <hip/hip_runtime.h>
#include <hip/hip_bf16.h>

typedef __attribute__((ext_vector_type(4))) float  f32x4;
typedef __attribute__((ext_vector_type(8))) short  short8;
typedef __attribute__((ext_vector_type(4))) short  short4v;

#define EMBED 4096
#define LR    512
#define KSEL  128
#define BATCH 8192

__device__ __forceinline__ short f2bf(float x) {
  union { float f; unsigned u; } c; c.f = x;
  unsigned r = c.u + 0x7FFFu + ((c.u >> 16) & 1u);  // RNE
  return (short)(r >> 16);
}

// K0: gather selected columns of W, emit two bf16 MFMA-packed layouts.
// Wp : [e/8][128 cols][8]  (B-operand for GEMM1: kk-dim = embed)
// Wtp: [c/8][4096 e ][8]  (B-operand for GEMM2: kk-dim = sel index)
__global__ __launch_bounds__(256) void pack_w_kernel(
    const float* __restrict__ W, const int* __restrict__ sel,
    short* __restrict__ Wp, short* __restrict__ Wtp) {
  int idx = blockIdx.x * 256 + threadIdx.x;   // 0 .. 4096*128-1
  int e = idx >> 7;
  int c = idx & 127;
  int r = sel[c];
  short v = f2bf(W[e * LR + r]);
  Wp [(((e >> 3) << 7) + c) * 8 + (e & 7)] = v;
  Wtp[(((c >> 3) << 12) + e) * 8 + (c & 7)] = v;
}

// K1: Tp(bf16, packed [kk/8][8192][8]) = (src - base) @ Wsel
// block = 16 rows, 4 waves; wave w covers T cols 32w..32w+31.
__global__ __launch_bounds__(256) void gemm1_kernel(
    const float* __restrict__ base, const float* __restrict__ src,
    const short* __restrict__ Wp, short* __restrict__ Tp) {
  __shared__ short Dl[1024];               // [8 kgrp][16 rows][8] bf16 = 2KB
  const int t  = threadIdx.x;
  const int w  = t >> 6, l = t & 63;
  const int lr = l & 15, lg = l >> 4;
  const int row0 = blockIdx.x * 16;

  // staging: thread t -> row sr, 4 consecutive kk starting at sk
  const int sr = t >> 4, sk = (t & 15) * 4;
  const float* bp = base + (size_t)(row0 + sr) * EMBED + sk;
  const float* sp = src  + (size_t)(row0 + sr) * EMBED + sk;
  const int wofs = (((sk >> 3) << 4) + sr) * 8 + (sk & 7);

  // Wp element base for this lane: ((lg)*128 + 32w + lr) * 8
  const short* wpb = Wp + ((lg << 7) + (w << 5) + lr) * 8;

  f32x4 acc0 = {0.f, 0.f, 0.f, 0.f}, acc1 = {0.f, 0.f, 0.f, 0.f};

  f32x4 vb = *(const f32x4*)bp;
  f32x4 vs = *(const f32x4*)sp;

  for (int kt = 0; kt < 64; ++kt) {
    __syncthreads();                       // protect LDS from prev readers
    short4v d;
    #pragma unroll
    for (int c = 0; c < 4; ++c) d[c] = f2bf(vs[c] - vb[c]);
    *(short4v*)&Dl[wofs] = d;
    if (kt < 63) {                         // prefetch next tile
      vb = *(const f32x4*)(bp + (kt + 1) * 64);
      vs = *(const f32x4*)(sp + (kt + 1) * 64);
    }
    __syncthreads();
    const int kc = kt * 64;
    #pragma unroll
    for (int ks = 0; ks < 2; ++ks) {
      short8 a  = *(const short8*)&Dl[((ks * 4 + lg) << 7) + lr * 8];
      short8 b0 = *(const short8*)(wpb + kc * 128 + ks * 4096);
      short8 b1 = *(const short8*)(wpb + kc * 128 + ks * 4096 + 128);
      acc0 = __builtin_amdgcn_mfma_f32_16x16x32_bf16(a, b0, acc0, 0, 0, 0);
      acc1 = __builtin_amdgcn_mfma_f32_16x16x32_bf16(a, b1, acc1, 0, 0, 0);
    }
  }

  // write T: lane holds T[row0 + 4*lg + r][32w + 16nf + lr], r=0..3
  #pragma unroll
  for (int nf = 0; nf < 2; ++nf) {
    f32x4 a = nf ? acc1 : acc0;
    int kk = (w << 5) + (nf << 4) + lr;
    short* dst = Tp + (size_t)(((kk >> 3) << 13) + row0 + (lg << 2)) * 8 + (kk & 7);
    #pragma unroll
    for (int r = 0; r < 4; ++r) dst[r * 8] = f2bf(a[r]);
  }
}

// K2: out = base + T @ Wsel^T. Block: 64 rows x 256 cols, 4 waves,
// wave w covers 64 cols. A (T-rows) in regs, 64 MFMAs/wave, fused add.
__global__ __launch_bounds__(256) void gemm2_kernel(
    const float* __restrict__ base, const short* __restrict__ Tp,
    const short* __restrict__ Wtp, float* __restrict__ out) {
  const int t  = threadIdx.x;
  const int w  = t >> 6, l = t & 63;
  const int lr = l & 15, lg = l >> 4;
  const int mt = blockIdx.x >> 4, nt = blockIdx.x & 15;
  const int row0 = mt * 64;
  const int col0 = nt * 256 + w * 64;

  short8 afr[4][4];
  #pragma unroll
  for (int m = 0; m < 4; ++m)
    #pragma unroll
    for (int ks = 0; ks < 4; ++ks)
      afr[m][ks] = *(const short8*)(Tp + (size_t)(((ks * 4 + lg) << 13) + row0 + m * 16 + lr) * 8);

  f32x4 acc[4][4];
  #pragma unroll
  for (int m = 0; m < 4; ++m)
    #pragma unroll
    for (int nf = 0; nf < 4; ++nf) acc[m][nf] = (f32x4){0.f, 0.f, 0.f, 0.f};

  #pragma unroll
  for (int nf = 0; nf < 4; ++nf) {
    short8 bfr[4];
    #pragma unroll
    for (int ks = 0; ks < 4; ++ks)
      bfr[ks] = *(const short8*)(Wtp + (size_t)(((ks * 4 + lg) << 12) + col0 + nf * 16 + lr) * 8);
    #pragma unroll
    for (int m = 0; m < 4; ++m)
      #pragma unroll
      for (int ks = 0; ks < 4; ++ks)
        acc[m][nf] = __builtin_amdgcn_mfma_f32_16x16x32_bf16(afr[m][ks], bfr[ks], acc[m][nf], 0, 0, 0);
  }

  // epilogue: lane holds out[row0+16m+4lg+r][col0+16nf+lr]
  #pragma unroll
  for (int m = 0; m < 4; ++m)
    #pragma unroll
    for (int r = 0; r < 4; ++r) {
      const size_t row = row0 + m * 16 + lg * 4 + r;
      #pragma unroll
      for (int nf = 0; nf < 4; ++nf) {
        const size_t o = row * EMBED + col0 + nf * 16 + lr;
        out[o] = base[o] + acc[m][nf][r];
      }
    }
}

extern "C" void kernel_launch(void* const* d_in, const int* in_sizes, int n_in,
                              void* d_out, int out_size, void* d_ws, size_t ws_size,
                              hipStream_t stream) {
  const float* base = (const float*)d_in[0];
  const float* src  = (const float*)d_in[1];
  const int*   sub  = (const int*)d_in[2];   // int32; only first 128 used
  const float* W    = (const float*)d_in[3];
  float* out = (float*)d_out;

  short* Wp  = (short*)d_ws;                 // 4096*128 bf16 = 1 MB
  short* Wtp = Wp  + EMBED * KSEL;           // 1 MB
  short* Tp  = Wtp + EMBED * KSEL;           // 8192*128 bf16 = 2 MB

  pack_w_kernel<<<EMBED * KSEL / 256, 256, 0, stream>>>(W, sub, Wp, Wtp);
  gemm1_kernel<<<BATCH / 16, 256, 0, stream>>>(base, src, Wp, Tp);
  gemm2_kernel<<<(BATCH / 64) * 16, 256, 0, stream>>>(base, Tp, Wtp, out);
}

// Round 2
// 140.160 us; speedup vs baseline: 1.0014x; 1.0014x over previous
//
#include <hip/hip_runtime.h>
#include <hip/hip_bf16.h>

typedef __attribute__((ext_vector_type(4))) float  f32x4;
typedef __attribute__((ext_vector_type(8))) short  short8;

#define EMBED 4096
#define LR    512
#define KSEL  128
#define BATCH 8192

__device__ __forceinline__ short f2bf(float x) {
  union { float f; unsigned u; } c; c.f = x;
  unsigned r = c.u + 0x7FFFu + ((c.u >> 16) & 1u);  // RNE
  return (short)(r >> 16);
}

// K0: gather selected columns of W, emit two bf16 MFMA-packed layouts.
// Wp : [e/8][128 cols][8]  (B-operand for GEMM1: kk-dim = embed)
// Wtp: [c/8][4096 e ][8]  (B-operand for GEMM2: kk-dim = sel index)
__global__ __launch_bounds__(256) void pack_w_kernel(
    const float* __restrict__ W, const int* __restrict__ sel,
    short* __restrict__ Wp, short* __restrict__ Wtp) {
  int idx = blockIdx.x * 256 + threadIdx.x;   // 0 .. 4096*128-1
  int e = idx >> 7;
  int c = idx & 127;
  int r = sel[c];
  short v = f2bf(W[e * LR + r]);
  Wp [(((e >> 3) << 7) + c) * 8 + (e & 7)] = v;
  Wtp[(((c >> 3) << 12) + e) * 8 + (c & 7)] = v;
}

// K1: Tp(bf16, packed [kk/8][8192][8]) = (src - base) @ Wsel
// Block = 512 threads = 8 waves, 16 rows. Wave w owns K-range [512w, 512w+512),
// all 128 T-cols (8 col-tiles). No LDS / no barriers in the main loop:
// A-fragments load straight from global (16 rows x 128B contiguous per wave),
// B-fragments stream from L2-resident packed W. One LDS reduce at the end.
__global__ __launch_bounds__(512) void gemm1_kernel(
    const float* __restrict__ base, const float* __restrict__ src,
    const short* __restrict__ Wp, short* __restrict__ Tp) {
  __shared__ f32x4 red[8 * 8 * 64];           // [wave][ntile][lane] = 64 KB
  const int t  = threadIdx.x;
  const int w  = t >> 6, l = t & 63;
  const int lr = l & 15, lg = l >> 4;
  const int row0 = blockIdx.x * 16;
  const int k0 = w * 512;

  const float* bp = base + (size_t)(row0 + lr) * EMBED + k0 + lg * 8;
  const float* sp = src  + (size_t)(row0 + lr) * EMBED + k0 + lg * 8;

  f32x4 acc[8];
  #pragma unroll
  for (int nf = 0; nf < 8; ++nf) acc[nf] = (f32x4){0.f, 0.f, 0.f, 0.f};

  #pragma unroll 4
  for (int it = 0; it < 16; ++it) {
    const int kb = it * 32;
    f32x4 b0 = *(const f32x4*)(bp + kb);
    f32x4 b1 = *(const f32x4*)(bp + kb + 4);
    f32x4 s0 = *(const f32x4*)(sp + kb);
    f32x4 s1 = *(const f32x4*)(sp + kb + 4);
    short8 a;
    #pragma unroll
    for (int j = 0; j < 4; ++j) {
      a[j]     = f2bf(s0[j] - b0[j]);
      a[4 + j] = f2bf(s1[j] - b1[j]);
    }
    const int e = k0 + kb + lg * 8;
    const short8* wrow = (const short8*)Wp + ((e >> 3) << 7);
    #pragma unroll
    for (int nf = 0; nf < 8; ++nf)
      acc[nf] = __builtin_amdgcn_mfma_f32_16x16x32_bf16(a, wrow[nf * 16 + lr], acc[nf], 0, 0, 0);
  }

  // cross-wave K-reduction through LDS (single barrier)
  #pragma unroll
  for (int nf = 0; nf < 8; ++nf) red[(w << 9) + (nf << 6) + l] = acc[nf];
  __syncthreads();
  {
    const int rl = t & 63, rnf = t >> 6;      // slot this thread reduces
    f32x4 s = red[(rnf << 6) + rl];
    #pragma unroll
    for (int w2 = 1; w2 < 8; ++w2) s += red[(w2 << 9) + (rnf << 6) + rl];
    // lane holds T[row0 + (rl>>4)*4 + r][kk = rnf*16 + (rl&15)]
    const int kk = rnf * 16 + (rl & 15);
    short* dst = Tp + (size_t)(((kk >> 3) << 13) + row0 + ((rl >> 4) << 2)) * 8 + (kk & 7);
    #pragma unroll
    for (int r = 0; r < 4; ++r) dst[r * 8] = f2bf(s[r]);
  }
}

// K2: out = base + T @ Wsel^T. Block: 64 rows x 256 cols, 4 waves,
// wave w covers 64 cols. A (T-rows) in regs, 64 MFMAs/wave, fused add.
__global__ __launch_bounds__(256) void gemm2_kernel(
    const float* __restrict__ base, const short* __restrict__ Tp,
    const short* __restrict__ Wtp, float* __restrict__ out) {
  const int t  = threadIdx.x;
  const int w  = t >> 6, l = t & 63;
  const int lr = l & 15, lg = l >> 4;
  const int mt = blockIdx.x >> 4, nt = blockIdx.x & 15;
  const int row0 = mt * 64;
  const int col0 = nt * 256 + w * 64;

  short8 afr[4][4];
  #pragma unroll
  for (int m = 0; m < 4; ++m)
    #pragma unroll
    for (int ks = 0; ks < 4; ++ks)
      afr[m][ks] = *(const short8*)(Tp + (size_t)(((ks * 4 + lg) << 13) + row0 + m * 16 + lr) * 8);

  f32x4 acc[4][4];
  #pragma unroll
  for (int m = 0; m < 4; ++m)
    #pragma unroll
    for (int nf = 0; nf < 4; ++nf) acc[m][nf] = (f32x4){0.f, 0.f, 0.f, 0.f};

  #pragma unroll
  for (int nf = 0; nf < 4; ++nf) {
    short8 bfr[4];
    #pragma unroll
    for (int ks = 0; ks < 4; ++ks)
      bfr[ks] = *(const short8*)(Wtp + (size_t)(((ks * 4 + lg) << 12) + col0 + nf * 16 + lr) * 8);
    #pragma unroll
    for (int m = 0; m < 4; ++m)
      #pragma unroll
      for (int ks = 0; ks < 4; ++ks)
        acc[m][nf] = __builtin_amdgcn_mfma_f32_16x16x32_bf16(afr[m][ks], bfr[ks], acc[m][nf], 0, 0, 0);
  }

  // epilogue: lane holds out[row0+16m+4lg+r][col0+16nf+lr]
  #pragma unroll
  for (int m = 0; m < 4; ++m)
    #pragma unroll
    for (int r = 0; r < 4; ++r) {
      const size_t row = row0 + m * 16 + lg * 4 + r;
      #pragma unroll
      for (int nf = 0; nf < 4; ++nf) {
        const size_t o = row * EMBED + col0 + nf * 16 + lr;
        out[o] = base[o] + acc[m][nf][r];
      }
    }
}

extern "C" void kernel_launch(void* const* d_in, const int* in_sizes, int n_in,
                              void* d_out, int out_size, void* d_ws, size_t ws_size,
                              hipStream_t stream) {
  const float* base = (const float*)d_in[0];
  const float* src  = (const float*)d_in[1];
  const int*   sub  = (const int*)d_in[2];   // int32; only first 128 used
  const float* W    = (const float*)d_in[3];
  float* out = (float*)d_out;

  short* Wp  = (short*)d_ws;                 // 4096*128 bf16 = 1 MB
  short* Wtp = Wp  + EMBED * KSEL;           // 1 MB
  short* Tp  = Wtp + EMBED * KSEL;           // 8192*128 bf16 = 2 MB

  pack_w_kernel<<<EMBED * KSEL / 256, 256, 0, stream>>>(W, sub, Wp, Wtp);
  gemm1_kernel<<<BATCH / 16, 512, 0, stream>>>(base, src, Wp, Tp);
  gemm2_kernel<<<(BATCH / 64) * 16, 256, 0, stream>>>(base, Tp, Wtp, out);
}

// Round 3
// 139.071 us; speedup vs baseline: 1.0093x; 1.0078x over previous
//
#include <hip/hip_runtime.h>
#include <hip/hip_bf16.h>

typedef __attribute__((ext_vector_type(4))) float  f32x4;
typedef __attribute__((ext_vector_type(8))) short  short8;
typedef unsigned int u32;

#define EMBED 4096
#define LR    512
#define KSEL  128
#define BATCH 8192

__device__ __forceinline__ short f2bf(float x) {
  union { float f; unsigned u; } c; c.f = x;
  unsigned r = c.u + 0x7FFFu + ((c.u >> 16) & 1u);  // RNE
  return (short)(r >> 16);
}

__device__ __forceinline__ void gload16(const void* g, void* l) {
  __builtin_amdgcn_global_load_lds((const __attribute__((address_space(1))) u32*)g,
                                   (__attribute__((address_space(3))) u32*)l, 16, 0, 0);
}

// K0: gather selected columns of W, emit two bf16 MFMA-packed layouts.
// Wp : [e/8][128 cols][8]  (B-operand for GEMM1: kk-dim = embed)
// Wtp: [c/8][4096 e ][8]  (B-operand for GEMM2: kk-dim = sel index)
__global__ __launch_bounds__(256) void pack_w_kernel(
    const float* __restrict__ W, const int* __restrict__ sel,
    short* __restrict__ Wp, short* __restrict__ Wtp) {
  int idx = blockIdx.x * 256 + threadIdx.x;   // 0 .. 4096*128-1
  int e = idx >> 7;
  int c = idx & 127;
  int r = sel[c];
  short v = f2bf(W[e * LR + r]);
  Wp [(((e >> 3) << 7) + c) * 8 + (e & 7)] = v;
  Wtp[(((c >> 3) << 12) + e) * 8 + (c & 7)] = v;
}

// K1: Tp(bf16, packed [kk/8][8192][8]) = (src - base) @ Wsel
// 512 blocks x 512 threads. Block = 16 rows, full K=4096.
// Waves 0-3: K in [0,2048), waves 4-7: [2048,4096); wave covers 32 T-cols.
// Per K-step (BK=128): global_load_lds stages both arrays/k-halves into
// double-buffered LDS (XOR-swizzled via pre-swizzled SOURCE addresses);
// one barrier per step; next-stage flies under current compute.
// LDS tile layout: chunk c (16B) in [0,2048): arr=c>>10, kh=(c>>9)&1,
// row=(c>>5)&15, ch=c&31; LDS[row][ch] holds global chunk ch^(row&7).
__global__ __launch_bounds__(512) void gemm1_kernel(
    const float* __restrict__ base, const float* __restrict__ src,
    const short* __restrict__ Wp, short* __restrict__ Tp) {
  __shared__ char smem[65536];                // 2 bufs x 32KB
  const int t  = threadIdx.x;
  const int w  = t >> 6, l = t & 63;
  const int lr = l & 15, lg = l >> 4;
  const int row0 = blockIdx.x * 16;
  const int kh  = w >> 2;                     // this wave's k-half
  const int nf0 = (w & 3) * 2;                // first of 2 col-tiles

  // staging: thread t stages chunks c_i = i*512 + t, i=0..3
  const int srow = t >> 5;                    // row for all 4 chunks
  const int schg = ((t & 31) ^ (srow & 7)) << 2;  // pre-swizzled f32 col
  const size_t soff = (size_t)(row0 + srow) * EMBED + schg;
  const float* g_b0 = base + soff;            // arr=base, kh=0
  const float* g_b1 = base + soff + 2048;     // arr=base, kh=1
  const float* g_s0 = src  + soff;            // arr=src,  kh=0
  const float* g_s1 = src  + soff + 2048;     // arr=src,  kh=1

  f32x4 acc0 = {0.f, 0.f, 0.f, 0.f}, acc1 = {0.f, 0.f, 0.f, 0.f};

  #define STAGE(s, b) do {                                            \
    char* d_ = smem + (b) * 32768 + t * 16;                           \
    gload16(g_b0 + (s) * 128, d_);                                    \
    gload16(g_b1 + (s) * 128, d_ + 8192);                             \
    gload16(g_s0 + (s) * 128, d_ + 16384);                            \
    gload16(g_s1 + (s) * 128, d_ + 24576);                            \
  } while (0)

  STAGE(0, 0);
  int b = 0;
  for (int s = 0; s < 16; ++s) {
    __syncthreads();                          // vmcnt(0) drain: buf b ready
    if (s + 1 < 16) STAGE(s + 1, b ^ 1);
    const char* tb = smem + b * 32768 + kh * 8192 + lr * 512;
    const int kgb = kh * 2048 + s * 128;      // global k base of this tile
    #pragma unroll
    for (int ksub = 0; ksub < 4; ++ksub) {
      const int kin = ksub * 32 + lg * 8;     // f32 idx within 128-wide tile
      const int c0 = (kin >> 2) ^ (lr & 7);
      const int c1 = ((kin >> 2) + 1) ^ (lr & 7);
      f32x4 b0 = *(const f32x4*)(tb + c0 * 16);
      f32x4 b1 = *(const f32x4*)(tb + c1 * 16);
      f32x4 s0 = *(const f32x4*)(tb + 16384 + c0 * 16);
      f32x4 s1 = *(const f32x4*)(tb + 16384 + c1 * 16);
      short8 a;
      #pragma unroll
      for (int j = 0; j < 4; ++j) {
        a[j]     = f2bf(s0[j] - b0[j]);
        a[4 + j] = f2bf(s1[j] - b1[j]);
      }
      const short8* wrow = (const short8*)Wp + (((kgb + kin) >> 3) << 7);
      acc0 = __builtin_amdgcn_mfma_f32_16x16x32_bf16(a, wrow[nf0 * 16 + lr],       acc0, 0, 0, 0);
      acc1 = __builtin_amdgcn_mfma_f32_16x16x32_bf16(a, wrow[(nf0 + 1) * 16 + lr], acc1, 0, 0, 0);
    }
    b ^= 1;
  }
  #undef STAGE

  // reduce the two k-halves (wave w with wave w+4) through LDS
  __syncthreads();
  f32x4* red = (f32x4*)smem;                  // 8 waves x 2 nf x 64 lanes
  red[w * 128 + l]      = acc0;
  red[w * 128 + 64 + l] = acc1;
  __syncthreads();
  {
    const int w03 = t >> 7, nf = (t >> 6) & 1, l2 = t & 63;
    f32x4 sum = red[w03 * 128 + nf * 64 + l2] + red[(w03 + 4) * 128 + nf * 64 + l2];
    const int kk = w03 * 32 + nf * 16 + (l2 & 15);
    short* dst = Tp + (size_t)(((kk >> 3) << 13) + row0 + ((l2 >> 4) << 2)) * 8 + (kk & 7);
    #pragma unroll
    for (int r = 0; r < 4; ++r) dst[r * 8] = f2bf(sum[r]);
  }
}

// K2: out = base + T @ Wsel^T. Block: 64 rows x 256 cols, 4 waves,
// wave w covers 64 cols. A (T-rows) in regs, 64 MFMAs/wave, fused add.
__global__ __launch_bounds__(256) void gemm2_kernel(
    const float* __restrict__ base, const short* __restrict__ Tp,
    const short* __restrict__ Wtp, float* __restrict__ out) {
  const int t  = threadIdx.x;
  const int w  = t >> 6, l = t & 63;
  const int lr = l & 15, lg = l >> 4;
  const int mt = blockIdx.x >> 4, nt = blockIdx.x & 15;
  const int row0 = mt * 64;
  const int col0 = nt * 256 + w * 64;

  short8 afr[4][4];
  #pragma unroll
  for (int m = 0; m < 4; ++m)
    #pragma unroll
    for (int ks = 0; ks < 4; ++ks)
      afr[m][ks] = *(const short8*)(Tp + (size_t)(((ks * 4 + lg) << 13) + row0 + m * 16 + lr) * 8);

  f32x4 acc[4][4];
  #pragma unroll
  for (int m = 0; m < 4; ++m)
    #pragma unroll
    for (int nf = 0; nf < 4; ++nf) acc[m][nf] = (f32x4){0.f, 0.f, 0.f, 0.f};

  #pragma unroll
  for (int nf = 0; nf < 4; ++nf) {
    short8 bfr[4];
    #pragma unroll
    for (int ks = 0; ks < 4; ++ks)
      bfr[ks] = *(const short8*)(Wtp + (size_t)(((ks * 4 + lg) << 12) + col0 + nf * 16 + lr) * 8);
    #pragma unroll
    for (int m = 0; m < 4; ++m)
      #pragma unroll
      for (int ks = 0; ks < 4; ++ks)
        acc[m][nf] = __builtin_amdgcn_mfma_f32_16x16x32_bf16(afr[m][ks], bfr[ks], acc[m][nf], 0, 0, 0);
  }

  // epilogue: lane holds out[row0+16m+4lg+r][col0+16nf+lr]
  #pragma unroll
  for (int m = 0; m < 4; ++m)
    #pragma unroll
    for (int r = 0; r < 4; ++r) {
      const size_t row = row0 + m * 16 + lg * 4 + r;
      #pragma unroll
      for (int nf = 0; nf < 4; ++nf) {
        const size_t o = row * EMBED + col0 + nf * 16 + lr;
        out[o] = base[o] + acc[m][nf][r];
      }
    }
}

extern "C" void kernel_launch(void* const* d_in, const int* in_sizes, int n_in,
                              void* d_out, int out_size, void* d_ws, size_t ws_size,
                              hipStream_t stream) {
  const float* base = (const float*)d_in[0];
  const float* src  = (const float*)d_in[1];
  const int*   sub  = (const int*)d_in[2];   // int32; only first 128 used
  const float* W    = (const float*)d_in[3];
  float* out = (float*)d_out;

  short* Wp  = (short*)d_ws;                 // 4096*128 bf16 = 1 MB
  short* Wtp = Wp  + EMBED * KSEL;           // 1 MB
  short* Tp  = Wtp + EMBED * KSEL;           // 8192*128 bf16 = 2 MB

  pack_w_kernel<<<EMBED * KSEL / 256, 256, 0, stream>>>(W, sub, Wp, Wtp);
  gemm1_kernel<<<BATCH / 16, 512, 0, stream>>>(base, src, Wp, Tp);
  gemm2_kernel<<<(BATCH / 64) * 16, 256, 0, stream>>>(base, Tp, Wtp, out);
}

// Round 4
// 126.039 us; speedup vs baseline: 1.1136x; 1.1034x over previous
//
#include <hip/hip_runtime.h>
#include <hip/hip_bf16.h>

typedef __attribute__((ext_vector_type(4))) float  f32x4;
typedef __attribute__((ext_vector_type(8))) short  short8;
typedef __attribute__((ext_vector_type(4))) short  short4v;

#define EMBED 4096
#define LR    512
#define KSEL  128
#define BATCH 8192
#define NSLICE 8
#define KSLICE 512

__device__ __forceinline__ short f2bf(float x) {
  union { float f; unsigned u; } c; c.f = x;
  unsigned r = c.u + 0x7FFFu + ((c.u >> 16) & 1u);  // RNE
  return (short)(r >> 16);
}
__device__ __forceinline__ float bf2f(short s) {
  union { unsigned u; float f; } c; c.u = ((unsigned)(unsigned short)s) << 16;
  return c.f;
}
__device__ __forceinline__ void storept(float* p, float v) { *p = v; }
__device__ __forceinline__ void storept(short* p, float v) { *p = f2bf(v); }
__device__ __forceinline__ void loadpart(const float* p, f32x4& a, f32x4& b) {
  a += *(const f32x4*)p; b += *(const f32x4*)(p + 4);
}
__device__ __forceinline__ void loadpart(const short* p, f32x4& a, f32x4& b) {
  short8 v = *(const short8*)p;
  #pragma unroll
  for (int j = 0; j < 4; ++j) { a[j] += bf2f(v[j]); b[j] += bf2f(v[4 + j]); }
}

// K0: gather selected columns of W, emit two bf16 MFMA-packed layouts.
// Wp : [e/8][128 cols][8]  (B-operand for GEMM1: kk-dim = embed)
// Wtp: [c/8][4096 e ][8]  (B-operand for GEMM2: kk-dim = sel index)
__global__ __launch_bounds__(256) void pack_w_kernel(
    const float* __restrict__ W, const int* __restrict__ sel,
    short* __restrict__ Wp, short* __restrict__ Wtp) {
  int idx = blockIdx.x * 256 + threadIdx.x;
  int e = idx >> 7;
  int c = idx & 127;
  int r = sel[c];
  short v = f2bf(W[e * LR + r]);
  Wp [(((e >> 3) << 7) + c) * 8 + (e & 7)] = v;
  Wtp[(((c >> 3) << 12) + e) * 8 + (c & 7)] = v;
}

// K1a: Tpart[slice] = (src-base)[:, k0:k0+512] @ Wsel[k0:k0+512, :]
// Grid 512 = 64 rowgroups x 8 kslices. Block 512 thr = 8 waves; wave w owns
// cols [16w,16w+16); B-frags (16 x short8 = 64 VGPR) preloaded ONCE.
// A streamed: 8 row-tiles x 4 ksteps; reg-staged loads issued 2 steps ahead,
// subtract+cvt, ds_write into XOR-swizzled dbuf D-tile; 1 barrier/step.
template<typename PT>
__global__ __launch_bounds__(512, 4) void gemm1a_kernel(
    const float* __restrict__ base, const float* __restrict__ src,
    const short* __restrict__ Wp, PT* __restrict__ Tpart) {
  __shared__ __align__(16) short D[2 * 2048];   // 2 bufs x 4KB
  const int t  = threadIdx.x;
  const int w  = t >> 6, l = t & 63;
  const int lr = l & 15, lg = l >> 4;
  const int rg = blockIdx.x & 63, slice = blockIdx.x >> 6;
  const int row0 = rg * 128;
  const int k0 = slice * KSLICE;

  short8 bfr[16];
  #pragma unroll
  for (int kg = 0; kg < 16; ++kg)
    bfr[kg] = *(const short8*)(Wp + (((((k0 >> 3) + kg * 4 + lg)) << 7) + w * 16 + lr) * 8);

  // staging: thread t -> D row t>>5, 4 bf16 at k-offset (t&31)*4
  const int srow  = t >> 5;
  const int sbyte = srow * 256 + ((((t & 31) >> 1) ^ (srow & 7)) << 4) + (t & 1) * 8;
  const float* bp = base + (size_t)(row0 + srow) * EMBED + k0 + (t & 31) * 4;
  const float* sp = src  + (size_t)(row0 + srow) * EMBED + k0 + (t & 31) * 4;

  // MFMA-read byte offsets (swizzled) per kg
  const int rsw = (lr & 7) << 4;
  const char* tb = (const char*)D + lr * 256;

  f32x4 vbA = *(const f32x4*)bp,          vsA = *(const f32x4*)sp;          // s=0
  f32x4 vbB = *(const f32x4*)(bp + 128),  vsB = *(const f32x4*)(sp + 128);  // s=1

  f32x4 acc = {0.f, 0.f, 0.f, 0.f};
  PT* tout = Tpart + (size_t)slice * BATCH * KSEL + (size_t)(row0 + lg * 4) * KSEL + w * 16 + lr;

  #define KSTEP(BUF, VB, VS, KG0, PF_OK, PF_OFF)                              \
    do {                                                                      \
      short4v d;                                                              \
      _Pragma("unroll")                                                       \
      for (int j = 0; j < 4; ++j) d[j] = f2bf(VS[j] - VB[j]);                 \
      *(short4v*)((char*)D + (BUF) * 4096 + sbyte) = d;                       \
      if (PF_OK) {                                                            \
        VB = *(const f32x4*)(bt + (PF_OFF));                                  \
        VS = *(const f32x4*)(st + (PF_OFF));                                  \
      }                                                                       \
      __syncthreads();                                                        \
      _Pragma("unroll")                                                       \
      for (int kg = 0; kg < 4; ++kg) {                                        \
        short8 a = *(const short8*)(tb + (BUF) * 4096 +                       \
                                    ((kg * 64 + lg * 16) ^ rsw));             \
        acc = __builtin_amdgcn_mfma_f32_16x16x32_bf16(a, bfr[(KG0) + kg],     \
                                                      acc, 0, 0, 0);          \
      }                                                                       \
    } while (0)

  for (int tile = 0; tile < 8; ++tile) {
    const float* bt = bp + (size_t)tile * 16 * EMBED;
    const float* st = sp + (size_t)tile * 16 * EMBED;
    const bool pf = (tile < 7);
    KSTEP(0, vbA, vsA, 0,  true, 256);                 // prefetch (tile, k2)
    KSTEP(1, vbB, vsB, 4,  true, 384);                 // prefetch (tile, k3)
    KSTEP(0, vbA, vsA, 8,  pf,   16 * EMBED);          // prefetch (tile+1, k0)
    KSTEP(1, vbB, vsB, 12, pf,   16 * EMBED + 128);    // prefetch (tile+1, k1)
    PT* o = tout + (size_t)tile * 16 * KSEL;
    #pragma unroll
    for (int r = 0; r < 4; ++r) storept(o + (size_t)r * KSEL, acc[r]);
    acc = (f32x4){0.f, 0.f, 0.f, 0.f};
  }
  #undef KSTEP
}

// K1b: Tp (packed bf16 [kk/8][8192][8]) = sum of 8 Tpart slices
template<typename PT>
__global__ __launch_bounds__(512) void reduce_kernel(
    const PT* __restrict__ Tpart, short* __restrict__ Tp) {
  const int tid = blockIdx.x * 512 + threadIdx.x;   // 0..131071
  const int kkg = tid & 15, row = tid >> 4;
  f32x4 s0 = {0.f, 0.f, 0.f, 0.f}, s1 = {0.f, 0.f, 0.f, 0.f};
  #pragma unroll
  for (int s = 0; s < NSLICE; ++s)
    loadpart(Tpart + ((size_t)s * BATCH + row) * KSEL + kkg * 8, s0, s1);
  short8 o;
  #pragma unroll
  for (int j = 0; j < 4; ++j) { o[j] = f2bf(s0[j]); o[4 + j] = f2bf(s1[j]); }
  *(short8*)(Tp + ((size_t)kkg * BATCH + row) * 8) = o;
}

// K2: out = base + T @ Wsel^T. Block: 64 rows x 256 cols, 4 waves.
__global__ __launch_bounds__(256) void gemm2_kernel(
    const float* __restrict__ base, const short* __restrict__ Tp,
    const short* __restrict__ Wtp, float* __restrict__ out) {
  const int t  = threadIdx.x;
  const int w  = t >> 6, l = t & 63;
  const int lr = l & 15, lg = l >> 4;
  const int mt = blockIdx.x >> 4, nt = blockIdx.x & 15;
  const int row0 = mt * 64;
  const int col0 = nt * 256 + w * 64;

  short8 afr[4][4];
  #pragma unroll
  for (int m = 0; m < 4; ++m)
    #pragma unroll
    for (int ks = 0; ks < 4; ++ks)
      afr[m][ks] = *(const short8*)(Tp + (size_t)(((ks * 4 + lg) << 13) + row0 + m * 16 + lr) * 8);

  f32x4 acc[4][4];
  #pragma unroll
  for (int m = 0; m < 4; ++m)
    #pragma unroll
    for (int nf = 0; nf < 4; ++nf) acc[m][nf] = (f32x4){0.f, 0.f, 0.f, 0.f};

  #pragma unroll
  for (int nf = 0; nf < 4; ++nf) {
    short8 bfr[4];
    #pragma unroll
    for (int ks = 0; ks < 4; ++ks)
      bfr[ks] = *(const short8*)(Wtp + (size_t)(((ks * 4 + lg) << 12) + col0 + nf * 16 + lr) * 8);
    #pragma unroll
    for (int m = 0; m < 4; ++m)
      #pragma unroll
      for (int ks = 0; ks < 4; ++ks)
        acc[m][nf] = __builtin_amdgcn_mfma_f32_16x16x32_bf16(afr[m][ks], bfr[ks], acc[m][nf], 0, 0, 0);
  }

  #pragma unroll
  for (int m = 0; m < 4; ++m)
    #pragma unroll
    for (int r = 0; r < 4; ++r) {
      const size_t row = row0 + m * 16 + lg * 4 + r;
      #pragma unroll
      for (int nf = 0; nf < 4; ++nf) {
        const size_t o = row * EMBED + col0 + nf * 16 + lr;
        out[o] = base[o] + acc[m][nf][r];
      }
    }
}

extern "C" void kernel_launch(void* const* d_in, const int* in_sizes, int n_in,
                              void* d_out, int out_size, void* d_ws, size_t ws_size,
                              hipStream_t stream) {
  const float* base = (const float*)d_in[0];
  const float* src  = (const float*)d_in[1];
  const int*   sub  = (const int*)d_in[2];
  const float* W    = (const float*)d_in[3];
  float* out = (float*)d_out;

  short* Wp  = (short*)d_ws;                       // 1 MB
  short* Wtp = Wp  + EMBED * KSEL;                 // 1 MB
  short* Tp  = Wtp + EMBED * KSEL;                 // 2 MB
  char*  rest = (char*)(Tp + BATCH * KSEL);        // offset 4 MB

  pack_w_kernel<<<EMBED * KSEL / 256, 256, 0, stream>>>(W, sub, Wp, Wtp);

  const size_t need_f32 = (size_t)4 * 1024 * 1024 +
                          (size_t)NSLICE * BATCH * KSEL * sizeof(float);
  if (ws_size >= need_f32) {
    float* Tpart = (float*)rest;                   // 32 MB
    gemm1a_kernel<float><<<512, 512, 0, stream>>>(base, src, Wp, Tpart);
    reduce_kernel<float><<<BATCH * 16 / 512, 512, 0, stream>>>(Tpart, Tp);
  } else {
    short* Tpart = (short*)rest;                   // 8 MB
    gemm1a_kernel<short><<<512, 512, 0, stream>>>(base, src, Wp, Tpart);
    reduce_kernel<short><<<BATCH * 16 / 512, 512, 0, stream>>>(Tpart, Tp);
  }

  gemm2_kernel<<<(BATCH / 64) * 16, 256, 0, stream>>>(base, Tp, Wtp, out);
}